// Round 1
// baseline (950.697 us; speedup 1.0000x reference)
//
#include <hip/hip_runtime.h>

#define B_ 16
#define S_ 12
#define N_ 325
#define E_ 2600
#define CIN_ 32
#define H_ 64
#define HEADS_ 4
#define COUT_ 12
#define BS_ (B_*S_)          // 192
#define ROWS_ (BS_*N_)       // 62400
#define EN_ (E_+N_)          // 2925
#define QK_ (HEADS_*H_)      // 256

// ---------------- degree / norm / CSR pointers ----------------
__global__ void k_deg(const int* __restrict__ ei, int* __restrict__ ptr_gcn,
                      int* __restrict__ ptr_att, float* __restrict__ dinv) {
  __shared__ int cnt[N_];
  for (int i = threadIdx.x; i < N_; i += blockDim.x) cnt[i] = 0;
  __syncthreads();
  for (int e = threadIdx.x; e < E_; e += blockDim.x)
    atomicAdd(&cnt[ei[E_ + e]], 1);   // col = target
  __syncthreads();
  for (int n = threadIdx.x; n < N_; n += blockDim.x)
    dinv[n] = rsqrtf((float)(cnt[n] + 1));
  if (threadIdx.x == 0) {
    int a = 0, g = 0;
    for (int n = 0; n < N_; n++) {
      ptr_att[n] = a; ptr_gcn[n] = g;
      a += cnt[n]; g += cnt[n] + 1;   // gcn bucket has +1 self-loop slot
    }
    ptr_att[N_] = a; ptr_gcn[N_] = g;
  }
}

// ---------------- deterministic CSR fill (stable rank) ----------------
__global__ void k_fill(const int* __restrict__ ei, const int* __restrict__ ptr_gcn,
                       const int* __restrict__ ptr_att, const float* __restrict__ dinv,
                       int* __restrict__ gcn_src, float* __restrict__ gcn_w,
                       int* __restrict__ att_src) {
  __shared__ int cols[E_];
  for (int i = threadIdx.x; i < E_; i += blockDim.x) cols[i] = ei[E_ + i];
  __syncthreads();
  int e = blockIdx.x * blockDim.x + threadIdx.x;
  if (e >= EN_) return;
  int t = (e < E_) ? cols[e] : (e - E_);
  int s = (e < E_) ? ei[e]   : (e - E_);
  int lim = (e < E_) ? e : E_;
  int rank = 0;
  for (int j = 0; j < lim; j++) rank += (cols[j] == t);
  int pos = ptr_gcn[t] + rank;
  gcn_src[pos] = s;
  gcn_w[pos] = dinv[s] * dinv[t];
  if (e < E_) att_src[ptr_att[t] + rank] = s;
}

// ---------------- simple LDS GEMM: C[row,0..63] = A[row,:K] @ W[K,64] ----------------
template<int K>
__global__ void k_gemm64(const float* __restrict__ A, const float* __restrict__ W,
                         float* __restrict__ C) {
  __shared__ float Wsh[K][64];
  __shared__ float Ash[16][K];
  int r0 = blockIdx.x * 16;
  for (int i = threadIdx.x; i < K * 64; i += 256) Wsh[i / 64][i % 64] = W[i];
  for (int i = threadIdx.x; i < 16 * K; i += 256)
    Ash[i / K][i % K] = A[(size_t)(r0 + i / K) * K + (i % K)];
  __syncthreads();
  int c = threadIdx.x & 63, rg = threadIdx.x >> 6;
  float acc[4] = {0.f, 0.f, 0.f, 0.f};
  for (int kk = 0; kk < K; kk++) {
    float w = Wsh[kk][c];
#pragma unroll
    for (int rr = 0; rr < 4; rr++) acc[rr] += Ash[rg * 4 + rr][kk] * w;
  }
#pragma unroll
  for (int rr = 0; rr < 4; rr++)
    C[(size_t)(r0 + rg * 4 + rr) * 64 + c] = acc[rr];
}

// ---------------- GCN message passing: h = relu(scatter(norm * hw) + b) ----------------
__global__ void k_mp(const float* __restrict__ hw, const int* __restrict__ ptr,
                     const int* __restrict__ src, const float* __restrict__ w,
                     const float* __restrict__ bias, float* __restrict__ hout) {
  int g = blockIdx.x * 4 + (threadIdx.x >> 6);   // (bs,n) index, grid exact
  int lane = threadIdx.x & 63;
  int n = g % N_, bs = g / N_;
  int p0 = ptr[n], p1 = ptr[n + 1];
  const float* base = hw + (size_t)bs * N_ * H_;
  float acc = 0.f;
  for (int s2 = p0; s2 < p1; s2++)
    acc += w[s2] * base[src[s2] * H_ + lane];
  hout[(size_t)g * H_ + lane] = fmaxf(acc + bias[lane], 0.f);
}

// ---------------- per-head q/k projection ----------------
__global__ void k_qk(const float* __restrict__ xt, const float* __restrict__ Wq,
                     const float* __restrict__ bq, const float* __restrict__ Wk,
                     const float* __restrict__ bk, int head,
                     float* __restrict__ qo, float* __restrict__ ko) {
  __shared__ float Wqs[64][64];
  __shared__ float Wks[64][64];
  __shared__ float Ash[16][64];
  int r0 = blockIdx.x * 16;
  for (int i = threadIdx.x; i < 64 * 64; i += 256) {
    int r = i / 64, c = i % 64;
    Wqs[r][c] = Wq[r * QK_ + head * 64 + c];
    Wks[r][c] = Wk[r * QK_ + head * 64 + c];
  }
  for (int i = threadIdx.x; i < 16 * 64; i += 256)
    Ash[i / 64][i % 64] = xt[(size_t)(r0 + i / 64) * 64 + (i % 64)];
  __syncthreads();
  int c = threadIdx.x & 63, rg = threadIdx.x >> 6;
  float aq[4] = {0.f, 0.f, 0.f, 0.f}, ak[4] = {0.f, 0.f, 0.f, 0.f};
  for (int kk = 0; kk < 64; kk++) {
    float wq = Wqs[kk][c], wk = Wks[kk][c];
#pragma unroll
    for (int rr = 0; rr < 4; rr++) {
      float a = Ash[rg * 4 + rr][kk];
      aq[rr] += a * wq; ak[rr] += a * wk;
    }
  }
  float bqv = bq[head * 64 + c], bkv = bk[head * 64 + c];
#pragma unroll
  for (int rr = 0; rr < 4; rr++) {
    int row = r0 + rg * 4 + rr;
    qo[(size_t)row * 64 + c] = aq[rr] + bqv;
    ko[(size_t)row * 64 + c] = ak[rr] + bkv;
  }
}

__device__ __forceinline__ float wave_max64(float v) {
#pragma unroll
  for (int o = 32; o; o >>= 1) v = fmaxf(v, __shfl_xor(v, o));
  return v;
}
__device__ __forceinline__ float wave_sum64(float v) {
#pragma unroll
  for (int o = 32; o; o >>= 1) v += __shfl_xor(v, o);
  return v;
}

// ---------------- fused attention: logits + online softmax + xt aggregation ----------------
__global__ void k_attn(const float* __restrict__ q, const float* __restrict__ k,
                       const float* __restrict__ xt, const int* __restrict__ ptr,
                       const int* __restrict__ src, float* __restrict__ z) {
  __shared__ float qs[4][64];
  int wid = threadIdx.x >> 6, lane = threadIdx.x & 63;
  int g = blockIdx.x * 4 + wid;   // grid exact: 15600*4 = 62400
  int n = g % N_, bs = g / N_;
  int p0 = ptr[n], p1 = ptr[n + 1];
  const float* kb = k + (size_t)bs * N_ * 64;
  const float* xb = xt + (size_t)bs * N_ * 64;
  qs[wid][lane] = q[(size_t)g * 64 + lane];
  __syncthreads();
  const float4* q4 = reinterpret_cast<const float4*>(&qs[wid][0]);
  float m = -INFINITY, den = 0.f, zacc = 0.f;
  for (int base = p0; base < p1; base += 64) {
    int slot = base + lane;
    bool valid = slot < p1;
    int sidx = valid ? src[slot] : 0;
    float logit = -INFINITY;
    if (valid) {
      const float4* k4 = reinterpret_cast<const float4*>(kb + (size_t)sidx * 64);
      float d = 0.f;
#pragma unroll
      for (int j = 0; j < 16; j++) {
        float4 kv = k4[j], qv = q4[j];
        d += qv.x * kv.x + qv.y * kv.y + qv.z * kv.z + qv.w * kv.w;
      }
      logit = d * 0.125f;   // 1/sqrt(64)
    }
    float cm = wave_max64(logit);
    float mnew = fmaxf(m, cm);
    float scale = __expf(m - mnew);   // m=-inf first chunk -> 0, mnew finite
    den *= scale; zacc *= scale;
    float w = valid ? __expf(logit - mnew) : 0.f;
    den += wave_sum64(w);
    int cnt = min(64, p1 - base);
    for (int s2 = 0; s2 < cnt; s2++) {
      float wss = __shfl(w, s2);
      int srcs = __shfl(sidx, s2);
      zacc += wss * xb[(size_t)srcs * 64 + lane];
    }
    m = mnew;
  }
  z[(size_t)g * 64 + lane] = (p1 > p0) ? zacc / (den + 1e-16f) : 0.f;
}

// ---------------- out slice: z@Wv + xt@Ws + bs + 1{deg>0} bv ----------------
__global__ void k_outslice(const float* __restrict__ z, const float* __restrict__ xt,
                           const float* __restrict__ Wv, const float* __restrict__ bv,
                           const float* __restrict__ Wsm, const float* __restrict__ bsm,
                           const int* __restrict__ ptr, int head,
                           float* __restrict__ out) {
  __shared__ float Wvs[64][64];
  __shared__ float Wss[64][64];
  __shared__ float Zs[16][64];
  __shared__ float Xs[16][64];
  int r0 = blockIdx.x * 16;
  for (int i = threadIdx.x; i < 64 * 64; i += 256) {
    int r = i / 64, c = i % 64;
    Wvs[r][c] = Wv[r * QK_ + head * 64 + c];
    Wss[r][c] = Wsm[r * QK_ + head * 64 + c];
  }
  for (int i = threadIdx.x; i < 16 * 64; i += 256) {
    int r = i / 64, c = i % 64;
    Zs[r][c] = z[(size_t)(r0 + r) * 64 + c];
    Xs[r][c] = xt[(size_t)(r0 + r) * 64 + c];
  }
  __syncthreads();
  int c = threadIdx.x & 63, rg = threadIdx.x >> 6;
  float acc[4] = {0.f, 0.f, 0.f, 0.f};
  for (int kk = 0; kk < 64; kk++) {
    float wv = Wvs[kk][c], ws = Wss[kk][c];
#pragma unroll
    for (int rr = 0; rr < 4; rr++)
      acc[rr] += Zs[rg * 4 + rr][kk] * wv + Xs[rg * 4 + rr][kk] * ws;
  }
  float bsv = bsm[head * 64 + c], bvv = bv[head * 64 + c];
#pragma unroll
  for (int rr = 0; rr < 4; rr++) {
    int row = r0 + rg * 4 + rr;
    int n = row % N_;
    bool has = ptr[n + 1] > ptr[n];
    out[(size_t)row * QK_ + head * 64 + c] = acc[rr] + bsv + (has ? bvv : 0.f);
  }
}

// ---------------- final projection: y[b,n,:] = sum_{s,j} out[b,s,n,j] Wl[s*256+j,:] + bl ----------------
__global__ void k_final(const float* __restrict__ out, const float* __restrict__ Wl,
                        const float* __restrict__ bl, float* __restrict__ y) {
  int b = blockIdx.x / N_, n = blockIdx.x % N_;
  int t = threadIdx.x;
  float acc[COUT_];
#pragma unroll
  for (int co = 0; co < COUT_; co++) acc[co] = 0.f;
  for (int s = 0; s < S_; s++) {
    float ov = out[((size_t)(b * S_ + s) * N_ + n) * QK_ + t];
    const float* wl = Wl + (size_t)(s * QK_ + t) * COUT_;
#pragma unroll
    for (int co = 0; co < COUT_; co++) acc[co] += ov * wl[co];
  }
#pragma unroll
  for (int co = 0; co < COUT_; co++) {
#pragma unroll
    for (int o = 32; o; o >>= 1) acc[co] += __shfl_down(acc[co], o);
  }
  __shared__ float part[4][COUT_];
  int wid = t >> 6, lane = t & 63;
  if (lane == 0) {
#pragma unroll
    for (int co = 0; co < COUT_; co++) part[wid][co] = acc[co];
  }
  __syncthreads();
  if (t < COUT_)
    y[(size_t)(b * N_ + n) * COUT_ + t] =
        part[0][t] + part[1][t] + part[2][t] + part[3][t] + bl[t];
}

extern "C" void kernel_launch(void* const* d_in, const int* in_sizes, int n_in,
                              void* d_out, int out_size, void* d_ws, size_t ws_size,
                              hipStream_t stream) {
  const float* x   = (const float*)d_in[0];
  const int*   ei  = (const int*)d_in[1];
  const float* Wg[4] = {(const float*)d_in[2], (const float*)d_in[4],
                        (const float*)d_in[6], (const float*)d_in[8]};
  const float* bg[4] = {(const float*)d_in[3], (const float*)d_in[5],
                        (const float*)d_in[7], (const float*)d_in[9]};
  const float* Wq = (const float*)d_in[10]; const float* bq = (const float*)d_in[11];
  const float* Wk = (const float*)d_in[12]; const float* bk = (const float*)d_in[13];
  const float* Wv = (const float*)d_in[14]; const float* bv = (const float*)d_in[15];
  const float* Ws = (const float*)d_in[16]; const float* bs = (const float*)d_in[17];
  const float* Wl = (const float*)d_in[18]; const float* bl = (const float*)d_in[19];
  float* y = (float*)d_out;

  char* p = (char*)d_ws;
  auto alloc = [&](size_t bytes) {
    char* r = p;
    p += (bytes + 255) & ~(size_t)255;
    return r;
  };
  float* dinv    = (float*)alloc(N_ * 4);
  int*   ptr_gcn = (int*)alloc((N_ + 1) * 4);
  int*   ptr_att = (int*)alloc((N_ + 1) * 4);
  int*   gcn_src = (int*)alloc(EN_ * 4);
  float* gcn_w   = (float*)alloc(EN_ * 4);
  int*   att_src = (int*)alloc(E_ * 4);
  float* h0 = (float*)alloc((size_t)ROWS_ * H_ * 4);
  float* h1 = (float*)alloc((size_t)ROWS_ * H_ * 4);
  float* qb = (float*)alloc((size_t)ROWS_ * H_ * 4);
  float* kb = (float*)alloc((size_t)ROWS_ * H_ * 4);
  float* zb = (float*)alloc((size_t)ROWS_ * H_ * 4);
  float* ob = (float*)alloc((size_t)ROWS_ * QK_ * 4);
  (void)ws_size; (void)in_sizes; (void)n_in; (void)out_size;

  k_deg<<<1, 512, 0, stream>>>(ei, ptr_gcn, ptr_att, dinv);
  k_fill<<<(EN_ + 255) / 256, 256, 0, stream>>>(ei, ptr_gcn, ptr_att, dinv,
                                                gcn_src, gcn_w, att_src);

  // GCN layer 0 (K=32 input), layers 1..3 (K=64)
  k_gemm64<CIN_><<<ROWS_ / 16, 256, 0, stream>>>(x, Wg[0], h1);
  k_mp<<<ROWS_ / 4, 256, 0, stream>>>(h1, ptr_gcn, gcn_src, gcn_w, bg[0], h0);
  for (int l = 1; l < 4; l++) {
    k_gemm64<H_><<<ROWS_ / 16, 256, 0, stream>>>(h0, Wg[l], h1);
    k_mp<<<ROWS_ / 4, 256, 0, stream>>>(h1, ptr_gcn, gcn_src, gcn_w, bg[l], h0);
  }

  // TransformerConv, head-serialized
  for (int head = 0; head < HEADS_; head++) {
    k_qk<<<ROWS_ / 16, 256, 0, stream>>>(h0, Wq, bq, Wk, bk, head, qb, kb);
    k_attn<<<ROWS_ / 4, 256, 0, stream>>>(qb, kb, h0, ptr_att, att_src, zb);
    k_outslice<<<ROWS_ / 16, 256, 0, stream>>>(zb, h0, Wv, bv, Ws, bs, ptr_att,
                                               head, ob);
  }

  k_final<<<B_ * N_, 256, 0, stream>>>(ob, Wl, bl, y);
}

// Round 2
// 729.193 us; speedup vs baseline: 1.3038x; 1.3038x over previous
//
#include <hip/hip_runtime.h>

#define B_ 16
#define S_ 12
#define N_ 325
#define E_ 2600
#define CIN_ 32
#define H_ 64
#define HEADS_ 4
#define COUT_ 12
#define BS_ (B_*S_)          // 192
#define ROWS_ (BS_*N_)       // 62400
#define EN_ (E_+N_)          // 2925
#define QK_ 256
#define HB_ (B_/2)           // 8 b per half
#define HBS_ (BS_/2)         // 96
#define HROWS_ (ROWS_/2)     // 31200

__device__ __forceinline__ int swz8(int bid, int cpx) {
  return (bid & 7) * cpx + (bid >> 3);   // grid must be multiple of 8
}

// ---------------- degree / norm / CSR pointers ----------------
__global__ void k_deg(const int* __restrict__ ei, int* __restrict__ ptr_gcn,
                      int* __restrict__ ptr_att, float* __restrict__ dinv) {
  __shared__ int cnt[N_];
  for (int i = threadIdx.x; i < N_; i += blockDim.x) cnt[i] = 0;
  __syncthreads();
  for (int e = threadIdx.x; e < E_; e += blockDim.x)
    atomicAdd(&cnt[ei[E_ + e]], 1);   // col = target
  __syncthreads();
  for (int n = threadIdx.x; n < N_; n += blockDim.x)
    dinv[n] = rsqrtf((float)(cnt[n] + 1));
  if (threadIdx.x == 0) {
    int a = 0, g = 0;
    for (int n = 0; n < N_; n++) {
      ptr_att[n] = a; ptr_gcn[n] = g;
      a += cnt[n]; g += cnt[n] + 1;   // gcn bucket has +1 self-loop slot
    }
    ptr_att[N_] = a; ptr_gcn[N_] = g;
  }
}

// ---------------- deterministic CSR fill (stable rank) ----------------
__global__ void k_fill(const int* __restrict__ ei, const int* __restrict__ ptr_gcn,
                       const int* __restrict__ ptr_att, const float* __restrict__ dinv,
                       int* __restrict__ gcn_src, float* __restrict__ gcn_w,
                       int* __restrict__ att_src) {
  __shared__ int cols[E_];
  for (int i = threadIdx.x; i < E_; i += blockDim.x) cols[i] = ei[E_ + i];
  __syncthreads();
  int e = blockIdx.x * blockDim.x + threadIdx.x;
  if (e >= EN_) return;
  int t = (e < E_) ? cols[e] : (e - E_);
  int s = (e < E_) ? ei[e]   : (e - E_);
  int lim = (e < E_) ? e : E_;
  int rank = 0;
  for (int j = 0; j < lim; j++) rank += (cols[j] == t);
  int pos = ptr_gcn[t] + rank;
  gcn_src[pos] = s;
  gcn_w[pos] = dinv[s] * dinv[t];
  if (e < E_) att_src[ptr_att[t] + rank] = s;
}

// ---------------- fused GCN layer: h' = relu( (sum_e w_e h[src_e]) @ W + b ) ----------------
// (aggregation commutes with the linear map W)
template<int K>
__global__ void k_gcn(const float* __restrict__ hin, const float* __restrict__ W,
                      const float* __restrict__ bias, const int* __restrict__ ptr,
                      const int* __restrict__ src, const float* __restrict__ wgt,
                      float* __restrict__ hout) {
  __shared__ float Wsh[K][64];
  for (int i = threadIdx.x; i < K * 64; i += 512) Wsh[i >> 6][i & 63] = W[i];
  __syncthreads();
  int bid = swz8(blockIdx.x, 975);            // 7800/8
  int wid = threadIdx.x >> 6, lane = threadIdx.x & 63;
  int g = bid * 8 + wid;                      // exact: 7800*8 = 62400
  int n = g % N_, bs = g / N_;
  int p0 = ptr[n], p1 = ptr[n + 1];
  const float* base = hin + (size_t)bs * N_ * K;
  float aggx = 0.f;
  for (int s2 = p0; s2 < p1; s2++) {
    float hv = 0.f;
    if (K == 64 || lane < K) hv = base[src[s2] * K + lane];
    aggx += wgt[s2] * hv;
  }
  float acc = bias[lane];
#pragma unroll 16
  for (int d = 0; d < K; d++)
    acc += __shfl(aggx, d) * Wsh[d][lane];
  hout[(size_t)g * 64 + lane] = fmaxf(acc, 0.f);
}

// ---------------- all-head q,k projection (col-tiled GEMM) ----------------
__global__ void k_qkall(const float* __restrict__ xt, const float* __restrict__ Wq,
                        const float* __restrict__ bq, const float* __restrict__ Wk,
                        const float* __restrict__ bk, int half,
                        float* __restrict__ qo, float* __restrict__ ko) {
  __shared__ float Wsh[64][64];
  __shared__ float Ash[16][64];
  int tc = blockIdx.y;                         // 0..7: 0-3 q cols, 4-7 k cols
  const float* Wsrc = (tc < 4) ? Wq : Wk;
  int c0 = (tc & 3) * 64;
  for (int i = threadIdx.x; i < 64 * 64; i += 256)
    Wsh[i >> 6][i & 63] = Wsrc[(i >> 6) * QK_ + c0 + (i & 63)];
  int r0 = blockIdx.x * 16;
  for (int i = threadIdx.x; i < 16 * 64; i += 256)
    Ash[i >> 6][i & 63] = xt[((size_t)half * HROWS_ + r0 + (i >> 6)) * 64 + (i & 63)];
  __syncthreads();
  int c = threadIdx.x & 63, rg = threadIdx.x >> 6;
  float acc[4] = {0.f, 0.f, 0.f, 0.f};
  for (int kk = 0; kk < 64; kk++) {
    float w = Wsh[kk][c];
#pragma unroll
    for (int rr = 0; rr < 4; rr++) acc[rr] += Ash[rg * 4 + rr][kk] * w;
  }
  const float* bsrc = (tc < 4) ? bq : bk;
  float bvv = bsrc[c0 + c];
  float* out = (tc < 4) ? qo : ko;
#pragma unroll
  for (int rr = 0; rr < 4; rr++)
    out[(size_t)(r0 + rg * 4 + rr) * QK_ + c0 + c] = acc[rr] + bvv;
}

// ---------------- fused multi-head attention: logits + online softmax + xt agg ----------------
// lane layout per 16-edge chunk: lane = el*4 + h (el = edge-in-chunk, h = head)
__global__ void k_attn4(const float* __restrict__ q, const float* __restrict__ k,
                        const float* __restrict__ xt, const int* __restrict__ ptr,
                        const int* __restrict__ src, int half,
                        float* __restrict__ z) {
  __shared__ float qs[4][4][72];               // [wave][head][64 + pad 8]
  int bid = swz8(blockIdx.x, 975);             // 7800/8
  int wid = threadIdx.x >> 6, lane = threadIdx.x & 63;
  int g = bid * 4 + wid;                       // local row within half
  int n = g % N_, bsl = g / N_;
  int p0 = ptr[n], p1 = ptr[n + 1];
  // stage q row (256 floats) into LDS, head-major with pad
  float4 qv = reinterpret_cast<const float4*>(q)[(size_t)g * 64 + lane];
  *reinterpret_cast<float4*>(&qs[wid][lane >> 4][(lane & 15) * 4]) = qv;
  __syncthreads();
  int h = lane & 3, el = lane >> 2;
  const float* kb = k + (size_t)bsl * N_ * QK_;
  const float* xb = xt + ((size_t)half * HBS_ + bsl) * N_ * 64;
  const float4* q4 = reinterpret_cast<const float4*>(&qs[wid][h][0]);
  float m = -INFINITY, den = 0.f;
  float zacc[4] = {0.f, 0.f, 0.f, 0.f};
  for (int base = p0; base < p1; base += 16) {
    int slot = base + el;
    bool valid = slot < p1;
    int sidx = valid ? src[slot] : 0;
    float logit = -INFINITY;
    if (valid) {
      const float4* k4 = reinterpret_cast<const float4*>(kb + (size_t)sidx * QK_ + h * 64);
      float d = 0.f;
#pragma unroll
      for (int j = 0; j < 16; j++) {
        float4 kv = k4[j], qq = q4[j];
        d += qq.x * kv.x + qq.y * kv.y + qq.z * kv.z + qq.w * kv.w;
      }
      logit = d * 0.125f;                      // 1/sqrt(64)
    }
    float cm = logit;
#pragma unroll
    for (int o = 4; o < 64; o <<= 1) cm = fmaxf(cm, __shfl_xor(cm, o));
    float mnew = fmaxf(m, cm);
    float scale = __expf(m - mnew);            // first chunk: exp(-inf)=0
    float w = valid ? __expf(logit - mnew) : 0.f;
    float wsum = w;
#pragma unroll
    for (int o = 4; o < 64; o <<= 1) wsum += __shfl_xor(wsum, o);
    den = den * scale + wsum;
#pragma unroll
    for (int h2 = 0; h2 < 4; h2++) zacc[h2] *= __shfl(scale, h2);
    int cnt = min(16, p1 - base);
    for (int e2 = 0; e2 < cnt; e2++) {
      int s_e = __shfl(sidx, e2 * 4);
      float xv = xb[(size_t)s_e * 64 + lane];
#pragma unroll
      for (int h2 = 0; h2 < 4; h2++)
        zacc[h2] += __shfl(w, e2 * 4 + h2) * xv;
    }
    m = mnew;
  }
  bool ok = p1 > p0;
#pragma unroll
  for (int h2 = 0; h2 < 4; h2++) {
    float dh = __shfl(den, h2);
    z[(size_t)g * QK_ + h2 * 64 + lane] = ok ? zacc[h2] / (dh + 1e-16f) : 0.f;
  }
}

// ---------------- all-head out slice: z@Wv + xt@Ws + bs + 1{deg>0} bv ----------------
__global__ void k_outslice(const float* __restrict__ z, const float* __restrict__ xt,
                           const float* __restrict__ Wv, const float* __restrict__ bv,
                           const float* __restrict__ Wsm, const float* __restrict__ bsm,
                           const int* __restrict__ ptr, int half,
                           float* __restrict__ out) {
  __shared__ float Wvs[64][64];
  __shared__ float Wss[64][64];
  __shared__ float Zs[16][64];
  __shared__ float Xs[16][64];
  int head = blockIdx.y;
  int c0 = head * 64;
  int r0 = blockIdx.x * 16;
  for (int i = threadIdx.x; i < 64 * 64; i += 256) {
    Wvs[i >> 6][i & 63] = Wv[(i >> 6) * QK_ + c0 + (i & 63)];
    Wss[i >> 6][i & 63] = Wsm[(i >> 6) * QK_ + c0 + (i & 63)];
  }
  for (int i = threadIdx.x; i < 16 * 64; i += 256) {
    Zs[i >> 6][i & 63] = z[(size_t)(r0 + (i >> 6)) * QK_ + c0 + (i & 63)];
    Xs[i >> 6][i & 63] = xt[((size_t)half * HROWS_ + r0 + (i >> 6)) * 64 + (i & 63)];
  }
  __syncthreads();
  int c = threadIdx.x & 63, rg = threadIdx.x >> 6;
  float acc[4] = {0.f, 0.f, 0.f, 0.f};
  for (int kk = 0; kk < 64; kk++) {
    float wv = Wvs[kk][c], wsv = Wss[kk][c];
#pragma unroll
    for (int rr = 0; rr < 4; rr++)
      acc[rr] += Zs[rg * 4 + rr][kk] * wv + Xs[rg * 4 + rr][kk] * wsv;
  }
  float bsv = bsm[c0 + c], bvv = bv[c0 + c];
#pragma unroll
  for (int rr = 0; rr < 4; rr++) {
    int row = r0 + rg * 4 + rr;
    int n = row % N_;
    bool has = ptr[n + 1] > ptr[n];
    out[(size_t)row * QK_ + c0 + c] = acc[rr] + bsv + (has ? bvv : 0.f);
  }
}

// ---------------- final projection per half ----------------
__global__ void k_final(const float* __restrict__ out, const float* __restrict__ Wl,
                        const float* __restrict__ bl, int half, float* __restrict__ y) {
  int bloc = blockIdx.x / N_, n = blockIdx.x % N_;
  int t = threadIdx.x;
  float acc[COUT_];
#pragma unroll
  for (int co = 0; co < COUT_; co++) acc[co] = 0.f;
  for (int s = 0; s < S_; s++) {
    float ov = out[((size_t)(bloc * S_ + s) * N_ + n) * QK_ + t];
    const float* wl = Wl + (size_t)(s * QK_ + t) * COUT_;
#pragma unroll
    for (int co = 0; co < COUT_; co++) acc[co] += ov * wl[co];
  }
#pragma unroll
  for (int co = 0; co < COUT_; co++) {
#pragma unroll
    for (int o = 32; o; o >>= 1) acc[co] += __shfl_down(acc[co], o);
  }
  __shared__ float part[4][COUT_];
  int wid = t >> 6, lane = t & 63;
  if (lane == 0) {
#pragma unroll
    for (int co = 0; co < COUT_; co++) part[wid][co] = acc[co];
  }
  __syncthreads();
  if (t < COUT_)
    y[((size_t)((half * HB_ + bloc) * N_) + n) * COUT_ + t] =
        part[0][t] + part[1][t] + part[2][t] + part[3][t] + bl[t];
}

extern "C" void kernel_launch(void* const* d_in, const int* in_sizes, int n_in,
                              void* d_out, int out_size, void* d_ws, size_t ws_size,
                              hipStream_t stream) {
  const float* x   = (const float*)d_in[0];
  const int*   ei  = (const int*)d_in[1];
  const float* Wg[4] = {(const float*)d_in[2], (const float*)d_in[4],
                        (const float*)d_in[6], (const float*)d_in[8]};
  const float* bg[4] = {(const float*)d_in[3], (const float*)d_in[5],
                        (const float*)d_in[7], (const float*)d_in[9]};
  const float* Wq = (const float*)d_in[10]; const float* bq = (const float*)d_in[11];
  const float* Wk = (const float*)d_in[12]; const float* bk = (const float*)d_in[13];
  const float* Wv = (const float*)d_in[14]; const float* bv = (const float*)d_in[15];
  const float* Ws = (const float*)d_in[16]; const float* bs = (const float*)d_in[17];
  const float* Wl = (const float*)d_in[18]; const float* bl = (const float*)d_in[19];
  float* y = (float*)d_out;

  char* p = (char*)d_ws;
  auto alloc = [&](size_t bytes) {
    char* r = p;
    p += (bytes + 255) & ~(size_t)255;
    return r;
  };
  float* dinv    = (float*)alloc(N_ * 4);
  int*   ptr_gcn = (int*)alloc((N_ + 1) * 4);
  int*   ptr_att = (int*)alloc((N_ + 1) * 4);
  int*   gcn_src = (int*)alloc(EN_ * 4);
  float* gcn_w   = (float*)alloc(EN_ * 4);
  int*   att_src = (int*)alloc(E_ * 4);
  float* h0 = (float*)alloc((size_t)ROWS_ * H_ * 4);       // 16 MB
  float* h1 = (float*)alloc((size_t)ROWS_ * H_ * 4);       // 16 MB
  float* qb = (float*)alloc((size_t)HROWS_ * QK_ * 4);     // 32 MB (z aliases)
  float* kb = (float*)alloc((size_t)HROWS_ * QK_ * 4);     // 32 MB
  float* ob = (float*)alloc((size_t)HROWS_ * QK_ * 4);     // 32 MB
  float* zb = qb;   // safe alias: q[g] consumed into LDS before z[g] written
  (void)ws_size; (void)in_sizes; (void)n_in; (void)out_size;

  k_deg<<<1, 512, 0, stream>>>(ei, ptr_gcn, ptr_att, dinv);
  k_fill<<<(EN_ + 255) / 256, 256, 0, stream>>>(ei, ptr_gcn, ptr_att, dinv,
                                                gcn_src, gcn_w, att_src);

  // fused GCN layers: x -> h0 -> h1 -> h0 -> h1  (xt = h1)
  k_gcn<CIN_><<<ROWS_ / 8, 512, 0, stream>>>(x,  Wg[0], bg[0], ptr_gcn, gcn_src, gcn_w, h0);
  k_gcn<H_>  <<<ROWS_ / 8, 512, 0, stream>>>(h0, Wg[1], bg[1], ptr_gcn, gcn_src, gcn_w, h1);
  k_gcn<H_>  <<<ROWS_ / 8, 512, 0, stream>>>(h1, Wg[2], bg[2], ptr_gcn, gcn_src, gcn_w, h0);
  k_gcn<H_>  <<<ROWS_ / 8, 512, 0, stream>>>(h0, Wg[3], bg[3], ptr_gcn, gcn_src, gcn_w, h1);

  for (int half = 0; half < 2; half++) {
    k_qkall<<<dim3(HROWS_ / 16, 8), 256, 0, stream>>>(h1, Wq, bq, Wk, bk, half, qb, kb);
    k_attn4<<<HROWS_ / 4, 256, 0, stream>>>(qb, kb, h1, ptr_att, att_src, half, zb);
    k_outslice<<<dim3(HROWS_ / 16, 4), 256, 0, stream>>>(zb, h1, Wv, bv, Ws, bs,
                                                         ptr_att, half, ob);
    k_final<<<HB_ * N_, 256, 0, stream>>>(ob, Wl, bl, half, y);
  }
}